// Round 11
// baseline (504.208 us; speedup 1.0000x reference)
//
#include <hip/hip_runtime.h>
#include <hip/hip_cooperative_groups.h>

namespace cg = cooperative_groups;

typedef short bf16x8 __attribute__((ext_vector_type(8)));
typedef float f32x4 __attribute__((ext_vector_type(4)));

__device__ __forceinline__ unsigned short f2bf(float f) {
    unsigned u = __float_as_uint(f);
    unsigned r = (u + 0x7fffu + ((u >> 16) & 1u)) >> 16;
    return (unsigned short)r;
}

// ---------------- cooperative build: prep + CSR in ONE dispatch -----------
// Phases (grid.sync between): A) W transposes + x cvt + zero deg/als,
// B) degree histogram, C) two-level scan, D) CSR fill.
__global__ __launch_bounds__(256) void k_build(
    const float* __restrict__ W1, unsigned short* __restrict__ W1T,
    const float* __restrict__ W2, unsigned short* __restrict__ W2T,
    const float* __restrict__ W3, unsigned short* __restrict__ W3T,
    const float* __restrict__ x, unsigned short* __restrict__ xb,
    const int* __restrict__ ei, int E, int N,
    int* __restrict__ deg, int* __restrict__ off, int* __restrict__ cur,
    int* __restrict__ csr, int* __restrict__ dstarr,
    float* __restrict__ zbase, int zcount,
    int DIN, int HC, int DOUT, int* __restrict__ blockSums)
{
    cg::grid_group grid = cg::this_grid();
    int tid = blockIdx.x * blockDim.x + threadIdx.x;
    int nthreads = gridDim.x * blockDim.x;

    // Phase A
    int n1 = DIN * HC, n2 = n1 + HC * HC, n3 = n2 + HC * DOUT, n4 = n3 + N * DIN;
    for (int i = tid; i < n4; i += nthreads) {
        if (i < n1) { int k = i / HC, n = i - k * HC; W1T[n * DIN + k] = f2bf(W1[i]); }
        else if (i < n2) { int j = i - n1; int k = j / HC, n = j - k * HC; W2T[n * HC + k] = f2bf(W2[j]); }
        else if (i < n3) { int j = i - n2; int k = j / DOUT, n = j - k * DOUT; W3T[n * HC + k] = f2bf(W3[j]); }
        else { int j = i - n3; xb[j] = f2bf(x[j]); }
    }
    for (int i = tid; i < N; i += nthreads) deg[i] = 0;
    for (int i = tid; i < zcount; i += nthreads) zbase[i] = 0.f;
    grid.sync();

    // Phase B
    for (int e = tid; e < E; e += nthreads) atomicAdd(&deg[ei[E + e]], 1);
    grid.sync();

    // Phase C1: intra-block inclusive scan of (deg+1)
    __shared__ int sm[256];
    int v = (tid < N) ? deg[tid] + 1 : 0;
    sm[threadIdx.x] = v;
    __syncthreads();
    for (int dd = 1; dd < 256; dd <<= 1) {
        int t2 = (threadIdx.x >= dd) ? sm[threadIdx.x - dd] : 0;
        __syncthreads();
        sm[threadIdx.x] += t2;
        __syncthreads();
    }
    int incl = sm[threadIdx.x];
    if (threadIdx.x == 255) blockSums[blockIdx.x] = incl;
    grid.sync();

    // Phase C2: block 0 scans block sums (inclusive)
    if (blockIdx.x == 0) {
        __shared__ int sb[256];
        sb[threadIdx.x] = blockSums[threadIdx.x];
        __syncthreads();
        for (int dd = 1; dd < 256; dd <<= 1) {
            int t2 = (threadIdx.x >= dd) ? sb[threadIdx.x - dd] : 0;
            __syncthreads();
            sb[threadIdx.x] += t2;
            __syncthreads();
        }
        blockSums[threadIdx.x] = sb[threadIdx.x];
        if (threadIdx.x == 0) off[N] = E + N;
    }
    grid.sync();

    // Phase C3: write off/cur
    if (tid < N) {
        int blockExcl = (blockIdx.x == 0) ? 0 : blockSums[blockIdx.x - 1];
        int excl = blockExcl + incl - v;
        off[tid] = excl;
        cur[tid] = excl;
    }
    grid.sync();

    // Phase D: fill CSR (+ self-loops)
    int M = E + N;
    for (int i = tid; i < M; i += nthreads) {
        if (i < E) {
            int s = ei[i], d = ei[E + i];
            int pos = atomicAdd(&cur[d], 1);
            csr[pos] = s; dstarr[pos] = d;
        } else {
            int nn = i - E;
            int pos = atomicAdd(&cur[nn], 1);
            csr[pos] = nn; dstarr[pos] = nn;
        }
    }
}

// ---------------- GEMM + fused attention-logit epilogue -------------------
// D[M,Nc] = A[M,K]@BT^T; epilogue: per-row partial dots with a_src/a_dst
// (tile cols lie within ONE head), r-shuffle reduce, atomicAdd into als/ald
// (zeroed by k_build). HT = heads; head = n0 / (Nc/HT).
template <bool OUTBF, int HT>
__global__ __launch_bounds__(256) void k_gemm(
    const unsigned short* __restrict__ A, const unsigned short* __restrict__ BT,
    void* __restrict__ D, const float* __restrict__ asrc, const float* __restrict__ adst,
    float* __restrict__ als, float* __restrict__ ald,
    int M, int K, int Nc, int tiles_n)
{
    int wid = blockIdx.x * (blockDim.x >> 6) + (threadIdx.x >> 6);
    int tiles_m = (M + 63) >> 6;
    if (wid >= tiles_m * tiles_n) return;
    int lane = threadIdx.x & 63;
    int tm = wid / tiles_n, tn = wid - tm * tiles_n;
    int m0 = tm << 6, n0 = tn << 6;
    int r = lane & 15, q = lane >> 4;

    const unsigned short* Arow[4];
    const unsigned short* Brow[4];
#pragma unroll
    for (int i = 0; i < 4; ++i) {
        int row = m0 + 16 * i + r; row = row < M ? row : M - 1;
        Arow[i] = A + (size_t)row * K + q * 8;
        Brow[i] = BT + (size_t)(n0 + 16 * i + r) * K + q * 8;
    }

    f32x4 acc[4][4] = {};
    bf16x8 a[4], b[4], a2[4], b2[4];
#pragma unroll
    for (int i = 0; i < 4; ++i) {
        a[i] = *(const bf16x8*)(Arow[i]);
        b[i] = *(const bf16x8*)(Brow[i]);
    }
    for (int k0 = 0; k0 < K; k0 += 32) {
        int kn = k0 + 32;
        if (kn < K) {
#pragma unroll
            for (int i = 0; i < 4; ++i) {
                a2[i] = *(const bf16x8*)(Arow[i] + kn);
                b2[i] = *(const bf16x8*)(Brow[i] + kn);
            }
        }
#pragma unroll
        for (int i = 0; i < 4; ++i)
#pragma unroll
            for (int j = 0; j < 4; ++j)
                acc[i][j] = __builtin_amdgcn_mfma_f32_16x16x32_bf16(a[i], b[j], acc[i][j], 0, 0, 0);
        if (kn < K) {
#pragma unroll
            for (int i = 0; i < 4; ++i) { a[i] = a2[i]; b[i] = b2[i]; }
        }
    }

    // C store
#pragma unroll
    for (int i = 0; i < 4; ++i) {
        int rowb = m0 + 16 * i + q * 4;
#pragma unroll
        for (int rr = 0; rr < 4; ++rr) {
            int row = rowb + rr;
            if (row < M) {
#pragma unroll
                for (int j = 0; j < 4; ++j) {
                    int col = n0 + 16 * j + r;
                    if (OUTBF)
                        ((unsigned short*)D)[(size_t)row * Nc + col] = f2bf(acc[i][j][rr]);
                    else
                        ((float*)D)[(size_t)row * Nc + col] = acc[i][j][rr];
                }
            }
        }
    }

    // fused attention-logit epilogue
    float asv[4], adv[4];
#pragma unroll
    for (int j = 0; j < 4; ++j) {
        int col = n0 + 16 * j + r;
        asv[j] = asrc[col];
        adv[j] = adst[col];
    }
    int head = n0 / (Nc / HT);
#pragma unroll
    for (int i = 0; i < 4; ++i) {
#pragma unroll
        for (int rr = 0; rr < 4; ++rr) {
            int row = m0 + 16 * i + q * 4 + rr;
            float ps = 0.f, pd = 0.f;
#pragma unroll
            for (int j = 0; j < 4; ++j) {
                float vv = acc[i][j][rr];
                ps += vv * asv[j];
                pd += vv * adv[j];
            }
#pragma unroll
            for (int dd = 1; dd < 16; dd <<= 1) {
                ps += __shfl_xor(ps, dd);
                pd += __shfl_xor(pd, dd);
            }
            if (r == 0 && row < M) {
                atomicAdd(&als[row * HT + head], ps);
                atomicAdd(&ald[row * HT + head], pd);
            }
        }
    }
}

// ---------------- edge alpha, SoA head planes: alpha[h*M + t] -------------
__global__ void k_alpha4(const float* __restrict__ als, const float* __restrict__ ald,
                         const int* __restrict__ csr, const int* __restrict__ dstarr,
                         float* __restrict__ alpha, int M)
{
    int t = blockIdx.x * blockDim.x + threadIdx.x;
    if (t >= M) return;
    int s = csr[t], d = dstarr[t];
    f32x4 a = *(const f32x4*)(als + (size_t)s * 4);
    f32x4 b = *(const f32x4*)(ald + (size_t)d * 4);
#pragma unroll
    for (int h = 0; h < 4; ++h) {
        float l = a[h] + b[h];
        l = l > 0.f ? l : 0.2f * l;
        alpha[(size_t)h * M + t] = __expf(l);
    }
}

// ---------------- aggr for HC=512, H=4, bf16 h, SoA alpha -----------------
// Wave = (node, head); 4 edge-groups x 16 lanes; lane owns 8 bf16 (16B).
// Slab-sequential grid (head-major) keeps gather L2-resident per XCD.
template <bool DOELU>
__global__ __launch_bounds__(256) void k_aggr4b(
    const unsigned short* __restrict__ h, const float* __restrict__ alpha,
    const int* __restrict__ off, const int* __restrict__ csr,
    const float* __restrict__ bias,
    unsigned short* __restrict__ outp, int N, int nodeBlocks, int M)
{
    int head = blockIdx.x / nodeBlocks;
    int nb = blockIdx.x - head * nodeBlocks;
    int n = nb * 4 + (threadIdx.x >> 6);
    if (n >= N) return;
    int lane = threadIdx.x & 63;
    int g = lane >> 4;            // edge group 0..3
    int p = lane & 15;            // channel-lane within group
    int s0 = off[n], s1 = off[n + 1];

    float acc[8] = {};
    float den = 0.f;
    const unsigned short* hbase = h + head * 128 + p * 8;
    const float* abase = alpha + (size_t)head * M;

    auto stage = [&](int tt, float& a, uint4& q) {
        int ss = csr[tt];
        a = abase[tt];
        q = *(const uint4*)(hbase + ((unsigned)ss << 9));
    };
    auto consume = [&](float a, const uint4& q) {
        den += a;
        unsigned wds[4] = {q.x, q.y, q.z, q.w};
#pragma unroll
        for (int wv = 0; wv < 4; ++wv) {
            acc[2 * wv]     += a * __uint_as_float(wds[wv] << 16);
            acc[2 * wv + 1] += a * __uint_as_float(wds[wv] & 0xffff0000u);
        }
    };

    int t = s0 + g;
    float exA, exB; uint4 hqA, hqB;
    if (t < s1) {
        stage(t, exA, hqA);
        for (;;) {
            int t1 = t + 4;
            bool h1 = t1 < s1;
            if (h1) stage(t1, exB, hqB);
            consume(exA, hqA);
            if (!h1) break;
            int t2 = t1 + 4;
            bool h2 = t2 < s1;
            if (h2) stage(t2, exA, hqA);
            consume(exB, hqB);
            if (!h2) break;
            t = t2;
        }
    }

    den += __shfl_xor(den, 16);
    den += __shfl_xor(den, 32);
#pragma unroll
    for (int j = 0; j < 8; ++j) {
        acc[j] += __shfl_xor(acc[j], 16);
        acc[j] += __shfl_xor(acc[j], 32);
    }

    if (g == 0) {
        float inv = 1.f / den;
        int cb = head * 128 + p * 8;
        unsigned ww[4];
#pragma unroll
        for (int wv = 0; wv < 4; ++wv) {
            float v0 = acc[2 * wv] * inv + bias[cb + 2 * wv];
            float v1 = acc[2 * wv + 1] * inv + bias[cb + 2 * wv + 1];
            if (DOELU) {
                v0 = v0 > 0.f ? v0 : expm1f(v0);
                v1 = v1 > 0.f ? v1 : expm1f(v1);
            }
            ww[wv] = (unsigned)f2bf(v0) | ((unsigned)f2bf(v1) << 16);
        }
        uint4 o; o.x = ww[0]; o.y = ww[1]; o.z = ww[2]; o.w = ww[3];
        *((uint4*)(outp + (size_t)n * 512 + cb)) = o;
    }
}

// ---------------- layer-3 aggr (HC=64, H=1, f32 h, inline alpha) ----------
__global__ __launch_bounds__(256) void k_aggr1b(
    const float* __restrict__ h, const float* __restrict__ als,
    const float* __restrict__ aldv, const int* __restrict__ off,
    const int* __restrict__ csr, const float* __restrict__ bias,
    float* __restrict__ outp, int N)
{
    int n = blockIdx.x * (blockDim.x >> 6) + (threadIdx.x >> 6);
    if (n >= N) return;
    int lane = threadIdx.x & 63;
    int g = lane >> 4;
    int p = lane & 15;
    int s0 = off[n], s1 = off[n + 1];
    float aldh = aldv[n];

    float acc[4] = {};
    float den = 0.f;
    const float* hbase = h + p * 4;

    auto stage = [&](int tt, float& a, uint4& q) {
        int ss = csr[tt];
        float l = als[ss] + aldh;
        l = l > 0.f ? l : 0.2f * l;
        a = __expf(l);
        q = *(const uint4*)(hbase + ((unsigned)ss << 6));
    };
    auto consume = [&](float a, const uint4& q) {
        den += a;
        acc[0] += a * __uint_as_float(q.x);
        acc[1] += a * __uint_as_float(q.y);
        acc[2] += a * __uint_as_float(q.z);
        acc[3] += a * __uint_as_float(q.w);
    };

    int t = s0 + g;
    float exA, exB; uint4 hqA, hqB;
    if (t < s1) {
        stage(t, exA, hqA);
        for (;;) {
            int t1 = t + 4;
            bool h1 = t1 < s1;
            if (h1) stage(t1, exB, hqB);
            consume(exA, hqA);
            if (!h1) break;
            int t2 = t1 + 4;
            bool h2 = t2 < s1;
            if (h2) stage(t2, exA, hqA);
            consume(exB, hqB);
            if (!h2) break;
            t = t2;
        }
    }

    den += __shfl_xor(den, 16);
    den += __shfl_xor(den, 32);
#pragma unroll
    for (int j = 0; j < 4; ++j) {
        acc[j] += __shfl_xor(acc[j], 16);
        acc[j] += __shfl_xor(acc[j], 32);
    }
    if (g == 0) {
        float inv = 1.f / den;
        f32x4 o;
#pragma unroll
        for (int j = 0; j < 4; ++j)
            o[j] = acc[j] * inv + bias[p * 4 + j];
        *((f32x4*)(outp + (size_t)n * 64 + p * 4)) = o;
    }
}

// --------------------------------------------------------------------------
extern "C" void kernel_launch(void* const* d_in, const int* in_sizes, int n_in,
                              void* d_out, int out_size, void* d_ws, size_t ws_size,
                              hipStream_t stream)
{
    const float* x   = (const float*)d_in[0];
    const int*   ei  = (const int*)d_in[1];
    const float* W1  = (const float*)d_in[2];
    const float* as1 = (const float*)d_in[3];
    const float* ad1 = (const float*)d_in[4];
    const float* b1  = (const float*)d_in[5];
    const float* W2  = (const float*)d_in[6];
    const float* as2 = (const float*)d_in[7];
    const float* ad2 = (const float*)d_in[8];
    const float* b2  = (const float*)d_in[9];
    const float* W3  = (const float*)d_in[10];
    const float* as3 = (const float*)d_in[11];
    const float* ad3 = (const float*)d_in[12];
    const float* b3  = (const float*)d_in[13];

    const int DIN = 256, HC = 512, DOUT = 64;
    int N = in_sizes[0] / DIN;
    int E = in_sizes[1] / 2;
    int M = E + N;

    // workspace carve-up
    char* w = (char*)d_ws;
    auto alloc = [&](size_t bytes) -> char* {
        char* p = w;
        w += (bytes + 255) & ~(size_t)255;
        return p;
    };
    int* deg    = (int*)alloc((size_t)N * 4);
    int* cur    = (int*)alloc((size_t)N * 4);
    int* off    = (int*)alloc((size_t)(N + 1) * 4);
    int* csr    = (int*)alloc((size_t)M * 4);
    int* dstarr = (int*)alloc((size_t)M * 4);
    int* blockSums = (int*)alloc(256 * 4);
    unsigned short* W1T = (unsigned short*)alloc((size_t)HC * DIN * 2);
    unsigned short* W2T = (unsigned short*)alloc((size_t)HC * HC * 2);
    unsigned short* W3T = (unsigned short*)alloc((size_t)DOUT * HC * 2);
    unsigned short* xb  = (unsigned short*)alloc((size_t)N * DIN * 2);
    unsigned short* act = (unsigned short*)alloc((size_t)N * HC * 2);
    unsigned short* hb  = (unsigned short*)alloc((size_t)N * HC * 2);
    float* hbuf  = (float*)alloc((size_t)N * DOUT * 4);
    float* alsb  = (float*)alloc((size_t)N * 18 * 4);   // als1,ald1,als2,ald2 (4N each) + als3,ald3 (N each)
    float* alpha = (float*)alloc((size_t)M * 4 * 4);

    float* als1 = alsb;
    float* ald1 = alsb + (size_t)N * 4;
    float* als2 = alsb + (size_t)N * 8;
    float* ald2 = alsb + (size_t)N * 12;
    float* als3 = alsb + (size_t)N * 16;
    float* ald3 = alsb + (size_t)N * 17;
    int zcount = N * 18;

    // ---- single cooperative build dispatch ----
    {
        const float* a0 = W1; unsigned short* a1 = W1T;
        const float* a2 = W2; unsigned short* a3 = W2T;
        const float* a4 = W3; unsigned short* a5 = W3T;
        const float* a6 = x;  unsigned short* a7 = xb;
        const int* a8 = ei; int a9 = E, a10 = N;
        int* a11 = deg; int* a12 = off; int* a13 = cur;
        int* a14 = csr; int* a15 = dstarr;
        float* a16 = alsb; int a17 = zcount;
        int a18 = DIN, a19 = HC, a20 = DOUT;
        int* a21 = blockSums;
        void* args[] = {&a0,&a1,&a2,&a3,&a4,&a5,&a6,&a7,&a8,&a9,&a10,&a11,&a12,
                        &a13,&a14,&a15,&a16,&a17,&a18,&a19,&a20,&a21};
        hipLaunchCooperativeKernel((void*)k_build, dim3(256), dim3(256), args, 0, stream);
    }

    int tiles_m = (N + 63) / 64;
    auto gemm_blocks = [&](int tn) { return (tiles_m * tn + 3) / 4; };
    int nwave_blocks = (N + 3) / 4;
    int nodeBlocks = (N + 3) / 4;
    int edge_blocks = (M + 255) / 256;

    // ---- layer 1 ----
    k_gemm<true, 4><<<gemm_blocks(HC / 64), 256, 0, stream>>>(
        xb, W1T, hb, as1, ad1, als1, ald1, N, DIN, HC, HC / 64);
    k_alpha4<<<edge_blocks, 256, 0, stream>>>(als1, ald1, csr, dstarr, alpha, M);
    k_aggr4b<true><<<4 * nodeBlocks, 256, 0, stream>>>(hb, alpha, off, csr, b1, act, N, nodeBlocks, M);

    // ---- layer 2 ----
    k_gemm<true, 4><<<gemm_blocks(HC / 64), 256, 0, stream>>>(
        act, W2T, hb, as2, ad2, als2, ald2, N, HC, HC, HC / 64);
    k_alpha4<<<edge_blocks, 256, 0, stream>>>(als2, ald2, csr, dstarr, alpha, M);
    k_aggr4b<true><<<4 * nodeBlocks, 256, 0, stream>>>(hb, alpha, off, csr, b2, act, N, nodeBlocks, M);

    // ---- layer 3 ----
    k_gemm<false, 1><<<gemm_blocks(1), 256, 0, stream>>>(
        act, W3T, hbuf, as3, ad3, als3, ald3, N, HC, DOUT, 1);
    k_aggr1b<<<nwave_blocks, 256, 0, stream>>>(hbuf, als3, ald3, off, csr, b3, (float*)d_out, N);
}

// Round 12
// 343.824 us; speedup vs baseline: 1.4665x; 1.4665x over previous
//
#include <hip/hip_runtime.h>

typedef short bf16x8 __attribute__((ext_vector_type(8)));
typedef float f32x4 __attribute__((ext_vector_type(4)));

__device__ __forceinline__ unsigned short f2bf(float f) {
    unsigned u = __float_as_uint(f);
    unsigned r = (u + 0x7fffu + ((u >> 16) & 1u)) >> 16;
    return (unsigned short)r;
}

// ---------------- CSR build ----------------
__global__ void k_hist(const int* __restrict__ ei, int E, int* deg) {
    int e = blockIdx.x * blockDim.x + threadIdx.x;
    if (e < E) atomicAdd(&deg[ei[E + e]], 1);
}
// scan with implicit +1 per node (self-loop)
__global__ void k_scan(const int* __restrict__ deg, int* __restrict__ off,
                       int* __restrict__ cur, int N) {
    __shared__ int sums[1024];
    int t = threadIdx.x;
    int chunk = (N + 1023) >> 10;
    int lo = t * chunk;
    int hi = lo + chunk; if (hi > N) hi = N;
    if (lo > N) lo = N;
    int s = 0;
    for (int i = lo; i < hi; ++i) s += deg[i] + 1;
    sums[t] = s;
    __syncthreads();
    for (int dd = 1; dd < 1024; dd <<= 1) {
        int v = (t >= dd) ? sums[t - dd] : 0;
        __syncthreads();
        sums[t] += v;
        __syncthreads();
    }
    int run = sums[t] - s;  // exclusive prefix
    for (int i = lo; i < hi; ++i) { off[i] = run; cur[i] = run; run += deg[i] + 1; }
    if (t == 1023) off[N] = run;
}
__global__ void k_fill(const int* __restrict__ ei, int E, int N,
                       int* cur, int* __restrict__ csr, int* __restrict__ dstarr) {
    int i = blockIdx.x * blockDim.x + threadIdx.x;
    if (i < E) {
        int s = ei[i], d = ei[E + i];
        int pos = atomicAdd(&cur[d], 1);
        csr[pos] = s;
        dstarr[pos] = d;
    } else if (i < E + N) {
        int nn = i - E;
        int pos = atomicAdd(&cur[nn], 1);
        csr[pos] = nn;
        dstarr[pos] = nn;
    }
}

// ---------------- fused prep: W transposes (f32->bf16), x cvt, zero als ----
__global__ void k_prep(const float* __restrict__ W1, unsigned short* __restrict__ W1T,
                       const float* __restrict__ W2, unsigned short* __restrict__ W2T,
                       const float* __restrict__ W3, unsigned short* __restrict__ W3T,
                       const float* __restrict__ x, unsigned short* __restrict__ xb,
                       float* __restrict__ zbase, int zcount,
                       int DIN, int HC, int DOUT, int N)
{
    int i = blockIdx.x * blockDim.x + threadIdx.x;
    int n1 = DIN * HC;            // W1: [DIN,HC] -> [HC,DIN]
    int n2 = n1 + HC * HC;
    int n3 = n2 + HC * DOUT;
    int n4 = n3 + N * DIN;
    int n5 = n4 + zcount;
    if (i < n1) {
        int k = i / HC, n = i - k * HC;
        W1T[n * DIN + k] = f2bf(W1[i]);
    } else if (i < n2) {
        int j = i - n1;
        int k = j / HC, n = j - k * HC;
        W2T[n * HC + k] = f2bf(W2[j]);
    } else if (i < n3) {
        int j = i - n2;
        int k = j / DOUT, n = j - k * DOUT;
        W3T[n * HC + k] = f2bf(W3[j]);
    } else if (i < n4) {
        int j = i - n3;
        xb[j] = f2bf(x[j]);
    } else if (i < n5) {
        zbase[i - n4] = 0.f;
    }
}

// ---------------- GEMM + fused attention-logit epilogue -------------------
// D[M,Nc] = A[M,K]@BT^T; epilogue: per-row partial dots with a_src/a_dst
// (tile cols lie within ONE head), r-shuffle reduce, atomicAdd into als/ald
// (zeroed by k_prep). HT = heads; head = n0 / (Nc/HT).
template <bool OUTBF, int HT>
__global__ __launch_bounds__(256) void k_gemm(
    const unsigned short* __restrict__ A, const unsigned short* __restrict__ BT,
    void* __restrict__ D, const float* __restrict__ asrc, const float* __restrict__ adst,
    float* __restrict__ als, float* __restrict__ ald,
    int M, int K, int Nc, int tiles_n)
{
    int wid = blockIdx.x * (blockDim.x >> 6) + (threadIdx.x >> 6);
    int tiles_m = (M + 63) >> 6;
    if (wid >= tiles_m * tiles_n) return;
    int lane = threadIdx.x & 63;
    int tm = wid / tiles_n, tn = wid - tm * tiles_n;
    int m0 = tm << 6, n0 = tn << 6;
    int r = lane & 15, q = lane >> 4;

    const unsigned short* Arow[4];
    const unsigned short* Brow[4];
#pragma unroll
    for (int i = 0; i < 4; ++i) {
        int row = m0 + 16 * i + r; row = row < M ? row : M - 1;
        Arow[i] = A + (size_t)row * K + q * 8;
        Brow[i] = BT + (size_t)(n0 + 16 * i + r) * K + q * 8;
    }

    f32x4 acc[4][4] = {};
    bf16x8 a[4], b[4], a2[4], b2[4];
#pragma unroll
    for (int i = 0; i < 4; ++i) {
        a[i] = *(const bf16x8*)(Arow[i]);
        b[i] = *(const bf16x8*)(Brow[i]);
    }
    for (int k0 = 0; k0 < K; k0 += 32) {
        int kn = k0 + 32;
        if (kn < K) {
#pragma unroll
            for (int i = 0; i < 4; ++i) {
                a2[i] = *(const bf16x8*)(Arow[i] + kn);
                b2[i] = *(const bf16x8*)(Brow[i] + kn);
            }
        }
#pragma unroll
        for (int i = 0; i < 4; ++i)
#pragma unroll
            for (int j = 0; j < 4; ++j)
                acc[i][j] = __builtin_amdgcn_mfma_f32_16x16x32_bf16(a[i], b[j], acc[i][j], 0, 0, 0);
        if (kn < K) {
#pragma unroll
            for (int i = 0; i < 4; ++i) { a[i] = a2[i]; b[i] = b2[i]; }
        }
    }

    // C store
#pragma unroll
    for (int i = 0; i < 4; ++i) {
        int rowb = m0 + 16 * i + q * 4;
#pragma unroll
        for (int rr = 0; rr < 4; ++rr) {
            int row = rowb + rr;
            if (row < M) {
#pragma unroll
                for (int j = 0; j < 4; ++j) {
                    int col = n0 + 16 * j + r;
                    if (OUTBF)
                        ((unsigned short*)D)[(size_t)row * Nc + col] = f2bf(acc[i][j][rr]);
                    else
                        ((float*)D)[(size_t)row * Nc + col] = acc[i][j][rr];
                }
            }
        }
    }

    // fused attention-logit epilogue
    float asv[4], adv[4];
#pragma unroll
    for (int j = 0; j < 4; ++j) {
        int col = n0 + 16 * j + r;
        asv[j] = asrc[col];
        adv[j] = adst[col];
    }
    int head = n0 / (Nc / HT);
#pragma unroll
    for (int i = 0; i < 4; ++i) {
#pragma unroll
        for (int rr = 0; rr < 4; ++rr) {
            int row = m0 + 16 * i + q * 4 + rr;
            float ps = 0.f, pd = 0.f;
#pragma unroll
            for (int j = 0; j < 4; ++j) {
                float vv = acc[i][j][rr];
                ps += vv * asv[j];
                pd += vv * adv[j];
            }
#pragma unroll
            for (int dd = 1; dd < 16; dd <<= 1) {
                ps += __shfl_xor(ps, dd);
                pd += __shfl_xor(pd, dd);
            }
            if (r == 0 && row < M) {
                atomicAdd(&als[row * HT + head], ps);
                atomicAdd(&ald[row * HT + head], pd);
            }
        }
    }
}

// ---------------- edge alpha, SoA head planes: alpha[h*M + t] -------------
__global__ void k_alpha4(const float* __restrict__ als, const float* __restrict__ ald,
                         const int* __restrict__ csr, const int* __restrict__ dstarr,
                         float* __restrict__ alpha, int M)
{
    int t = blockIdx.x * blockDim.x + threadIdx.x;
    if (t >= M) return;
    int s = csr[t], d = dstarr[t];
    f32x4 a = *(const f32x4*)(als + (size_t)s * 4);
    f32x4 b = *(const f32x4*)(ald + (size_t)d * 4);
#pragma unroll
    for (int h = 0; h < 4; ++h) {
        float l = a[h] + b[h];
        l = l > 0.f ? l : 0.2f * l;
        alpha[(size_t)h * M + t] = __expf(l);
    }
}

// ---------------- aggr for HC=512, H=4, bf16 h, SoA alpha -----------------
// Wave = (node, head); 4 edge-groups x 16 lanes; lane owns 8 bf16 (16B).
// Slab-sequential grid (head-major) keeps gather L2-resident per XCD.
template <bool DOELU>
__global__ __launch_bounds__(256) void k_aggr4b(
    const unsigned short* __restrict__ h, const float* __restrict__ alpha,
    const int* __restrict__ off, const int* __restrict__ csr,
    const float* __restrict__ bias,
    unsigned short* __restrict__ outp, int N, int nodeBlocks, int M)
{
    int head = blockIdx.x / nodeBlocks;
    int nb = blockIdx.x - head * nodeBlocks;
    int n = nb * 4 + (threadIdx.x >> 6);
    if (n >= N) return;
    int lane = threadIdx.x & 63;
    int g = lane >> 4;            // edge group 0..3
    int p = lane & 15;            // channel-lane within group
    int s0 = off[n], s1 = off[n + 1];

    float acc[8] = {};
    float den = 0.f;
    const unsigned short* hbase = h + head * 128 + p * 8;
    const float* abase = alpha + (size_t)head * M;

    auto stage = [&](int tt, float& a, uint4& q) {
        int ss = csr[tt];
        a = abase[tt];
        q = *(const uint4*)(hbase + ((unsigned)ss << 9));
    };
    auto consume = [&](float a, const uint4& q) {
        den += a;
        unsigned wds[4] = {q.x, q.y, q.z, q.w};
#pragma unroll
        for (int wv = 0; wv < 4; ++wv) {
            acc[2 * wv]     += a * __uint_as_float(wds[wv] << 16);
            acc[2 * wv + 1] += a * __uint_as_float(wds[wv] & 0xffff0000u);
        }
    };

    int t = s0 + g;
    float exA, exB; uint4 hqA, hqB;
    if (t < s1) {
        stage(t, exA, hqA);
        for (;;) {
            int t1 = t + 4;
            bool h1 = t1 < s1;
            if (h1) stage(t1, exB, hqB);
            consume(exA, hqA);
            if (!h1) break;
            int t2 = t1 + 4;
            bool h2 = t2 < s1;
            if (h2) stage(t2, exA, hqA);
            consume(exB, hqB);
            if (!h2) break;
            t = t2;
        }
    }

    den += __shfl_xor(den, 16);
    den += __shfl_xor(den, 32);
#pragma unroll
    for (int j = 0; j < 8; ++j) {
        acc[j] += __shfl_xor(acc[j], 16);
        acc[j] += __shfl_xor(acc[j], 32);
    }

    if (g == 0) {
        float inv = 1.f / den;
        int cb = head * 128 + p * 8;
        unsigned ww[4];
#pragma unroll
        for (int wv = 0; wv < 4; ++wv) {
            float v0 = acc[2 * wv] * inv + bias[cb + 2 * wv];
            float v1 = acc[2 * wv + 1] * inv + bias[cb + 2 * wv + 1];
            if (DOELU) {
                v0 = v0 > 0.f ? v0 : expm1f(v0);
                v1 = v1 > 0.f ? v1 : expm1f(v1);
            }
            ww[wv] = (unsigned)f2bf(v0) | ((unsigned)f2bf(v1) << 16);
        }
        uint4 o; o.x = ww[0]; o.y = ww[1]; o.z = ww[2]; o.w = ww[3];
        *((uint4*)(outp + (size_t)n * 512 + cb)) = o;
    }
}

// ---------------- layer-3 aggr (HC=64, H=1, f32 h, inline alpha) ----------
__global__ __launch_bounds__(256) void k_aggr1b(
    const float* __restrict__ h, const float* __restrict__ als,
    const float* __restrict__ aldv, const int* __restrict__ off,
    const int* __restrict__ csr, const float* __restrict__ bias,
    float* __restrict__ outp, int N)
{
    int n = blockIdx.x * (blockDim.x >> 6) + (threadIdx.x >> 6);
    if (n >= N) return;
    int lane = threadIdx.x & 63;
    int g = lane >> 4;
    int p = lane & 15;
    int s0 = off[n], s1 = off[n + 1];
    float aldh = aldv[n];

    float acc[4] = {};
    float den = 0.f;
    const float* hbase = h + p * 4;

    auto stage = [&](int tt, float& a, uint4& q) {
        int ss = csr[tt];
        float l = als[ss] + aldh;
        l = l > 0.f ? l : 0.2f * l;
        a = __expf(l);
        q = *(const uint4*)(hbase + ((unsigned)ss << 6));
    };
    auto consume = [&](float a, const uint4& q) {
        den += a;
        acc[0] += a * __uint_as_float(q.x);
        acc[1] += a * __uint_as_float(q.y);
        acc[2] += a * __uint_as_float(q.z);
        acc[3] += a * __uint_as_float(q.w);
    };

    int t = s0 + g;
    float exA, exB; uint4 hqA, hqB;
    if (t < s1) {
        stage(t, exA, hqA);
        for (;;) {
            int t1 = t + 4;
            bool h1 = t1 < s1;
            if (h1) stage(t1, exB, hqB);
            consume(exA, hqA);
            if (!h1) break;
            int t2 = t1 + 4;
            bool h2 = t2 < s1;
            if (h2) stage(t2, exA, hqA);
            consume(exB, hqB);
            if (!h2) break;
            t = t2;
        }
    }

    den += __shfl_xor(den, 16);
    den += __shfl_xor(den, 32);
#pragma unroll
    for (int j = 0; j < 4; ++j) {
        acc[j] += __shfl_xor(acc[j], 16);
        acc[j] += __shfl_xor(acc[j], 32);
    }
    if (g == 0) {
        float inv = 1.f / den;
        f32x4 o;
#pragma unroll
        for (int j = 0; j < 4; ++j)
            o[j] = acc[j] * inv + bias[p * 4 + j];
        *((f32x4*)(outp + (size_t)n * 64 + p * 4)) = o;
    }
}

// --------------------------------------------------------------------------
extern "C" void kernel_launch(void* const* d_in, const int* in_sizes, int n_in,
                              void* d_out, int out_size, void* d_ws, size_t ws_size,
                              hipStream_t stream)
{
    const float* x   = (const float*)d_in[0];
    const int*   ei  = (const int*)d_in[1];
    const float* W1  = (const float*)d_in[2];
    const float* as1 = (const float*)d_in[3];
    const float* ad1 = (const float*)d_in[4];
    const float* b1  = (const float*)d_in[5];
    const float* W2  = (const float*)d_in[6];
    const float* as2 = (const float*)d_in[7];
    const float* ad2 = (const float*)d_in[8];
    const float* b2  = (const float*)d_in[9];
    const float* W3  = (const float*)d_in[10];
    const float* as3 = (const float*)d_in[11];
    const float* ad3 = (const float*)d_in[12];
    const float* b3  = (const float*)d_in[13];

    const int DIN = 256, HC = 512, DOUT = 64;
    int N = in_sizes[0] / DIN;
    int E = in_sizes[1] / 2;
    int M = E + N;

    // workspace carve-up
    char* w = (char*)d_ws;
    auto alloc = [&](size_t bytes) -> char* {
        char* p = w;
        w += (bytes + 255) & ~(size_t)255;
        return p;
    };
    int* deg    = (int*)alloc((size_t)N * 4);
    int* cur    = (int*)alloc((size_t)N * 4);
    int* off    = (int*)alloc((size_t)(N + 1) * 4);
    int* csr    = (int*)alloc((size_t)M * 4);
    int* dstarr = (int*)alloc((size_t)M * 4);
    unsigned short* W1T = (unsigned short*)alloc((size_t)HC * DIN * 2);
    unsigned short* W2T = (unsigned short*)alloc((size_t)HC * HC * 2);
    unsigned short* W3T = (unsigned short*)alloc((size_t)DOUT * HC * 2);
    unsigned short* xb  = (unsigned short*)alloc((size_t)N * DIN * 2);
    unsigned short* act = (unsigned short*)alloc((size_t)N * HC * 2);
    unsigned short* hb  = (unsigned short*)alloc((size_t)N * HC * 2);
    float* hbuf  = (float*)alloc((size_t)N * DOUT * 4);
    float* alsb  = (float*)alloc((size_t)N * 18 * 4);   // als1,ald1,als2,ald2 (4N each) + als3,ald3 (N each)
    float* alpha = (float*)alloc((size_t)M * 4 * 4);

    float* als1 = alsb;
    float* ald1 = alsb + (size_t)N * 4;
    float* als2 = alsb + (size_t)N * 8;
    float* ald2 = alsb + (size_t)N * 12;
    float* als3 = alsb + (size_t)N * 16;
    float* ald3 = alsb + (size_t)N * 17;
    int zcount = N * 18;

    // ---- CSR build + prep (zeroes als/ald for fused epilogue) ----
    hipMemsetAsync(deg, 0, (size_t)N * 4, stream);
    k_hist<<<(E + 255) / 256, 256, 0, stream>>>(ei, E, deg);
    int prep_total = DIN * HC + HC * HC + HC * DOUT + N * DIN + zcount;
    k_prep<<<(prep_total + 255) / 256, 256, 0, stream>>>(
        W1, W1T, W2, W2T, W3, W3T, x, xb, alsb, zcount, DIN, HC, DOUT, N);
    k_scan<<<1, 1024, 0, stream>>>(deg, off, cur, N);
    k_fill<<<(M + 255) / 256, 256, 0, stream>>>(ei, E, N, cur, csr, dstarr);

    int tiles_m = (N + 63) / 64;
    auto gemm_blocks = [&](int tn) { return (tiles_m * tn + 3) / 4; };
    int nwave_blocks = (N + 3) / 4;
    int nodeBlocks = (N + 3) / 4;
    int edge_blocks = (M + 255) / 256;

    // ---- layer 1 ----
    k_gemm<true, 4><<<gemm_blocks(HC / 64), 256, 0, stream>>>(
        xb, W1T, hb, as1, ad1, als1, ald1, N, DIN, HC, HC / 64);
    k_alpha4<<<edge_blocks, 256, 0, stream>>>(als1, ald1, csr, dstarr, alpha, M);
    k_aggr4b<true><<<4 * nodeBlocks, 256, 0, stream>>>(hb, alpha, off, csr, b1, act, N, nodeBlocks, M);

    // ---- layer 2 ----
    k_gemm<true, 4><<<gemm_blocks(HC / 64), 256, 0, stream>>>(
        act, W2T, hb, as2, ad2, als2, ald2, N, HC, HC, HC / 64);
    k_alpha4<<<edge_blocks, 256, 0, stream>>>(als2, ald2, csr, dstarr, alpha, M);
    k_aggr4b<true><<<4 * nodeBlocks, 256, 0, stream>>>(hb, alpha, off, csr, b2, act, N, nodeBlocks, M);

    // ---- layer 3 ----
    k_gemm<false, 1><<<gemm_blocks(1), 256, 0, stream>>>(
        act, W3T, hbuf, as3, ad3, als3, ald3, N, HC, DOUT, 1);
    k_aggr1b<<<nwave_blocks, 256, 0, stream>>>(hbuf, als3, ald3, off, csr, b3, (float*)d_out, N);
}

// Round 13
// 317.420 us; speedup vs baseline: 1.5885x; 1.0832x over previous
//
#include <hip/hip_runtime.h>

typedef short bf16x8 __attribute__((ext_vector_type(8)));
typedef float f32x4 __attribute__((ext_vector_type(4)));

__device__ __forceinline__ unsigned short f2bf(float f) {
    unsigned u = __float_as_uint(f);
    unsigned r = (u + 0x7fffu + ((u >> 16) & 1u)) >> 16;
    return (unsigned short)r;
}

// ---------------- prep: W transposes, x cvt, csr=-1 init, degree hist ----
// deg is zeroed by a preceding hipMemsetAsync (stream-ordered), so the
// hist section's atomics are safe within this kernel.
__global__ void k_prep(const float* __restrict__ W1, unsigned short* __restrict__ W1T,
                       const float* __restrict__ W2, unsigned short* __restrict__ W2T,
                       const float* __restrict__ W3, unsigned short* __restrict__ W3T,
                       const float* __restrict__ x, unsigned short* __restrict__ xb,
                       int* __restrict__ csr, int Mcap,
                       const int* __restrict__ ei, int E, int* __restrict__ deg,
                       int DIN, int HC, int DOUT, int N)
{
    int i = blockIdx.x * blockDim.x + threadIdx.x;
    int n1 = DIN * HC;
    int n2 = n1 + HC * HC;
    int n3 = n2 + HC * DOUT;
    int n4 = n3 + N * DIN;
    int n5 = n4 + Mcap;
    int n6 = n5 + E;
    if (i < n1) {
        int k = i / HC, n = i - k * HC;
        W1T[n * DIN + k] = f2bf(W1[i]);
    } else if (i < n2) {
        int j = i - n1;
        int k = j / HC, n = j - k * HC;
        W2T[n * HC + k] = f2bf(W2[j]);
    } else if (i < n3) {
        int j = i - n2;
        int k = j / DOUT, n = j - k * DOUT;
        W3T[n * HC + k] = f2bf(W3[j]);
    } else if (i < n4) {
        int j = i - n3;
        xb[j] = f2bf(x[j]);
    } else if (i < n5) {
        csr[i - n4] = -1;           // pad sentinel
    } else if (i < n6) {
        atomicAdd(&deg[ei[E + (i - n5)]], 1);
    }
}

// scan of (deg+1) rounded up to multiple of 4 (padded segments)
__global__ void k_scan(const int* __restrict__ deg, int* __restrict__ off,
                       int* __restrict__ cur, int N) {
    __shared__ int sums[1024];
    int t = threadIdx.x;
    int chunk = (N + 1023) >> 10;
    int lo = t * chunk;
    int hi = lo + chunk; if (hi > N) hi = N;
    if (lo > N) lo = N;
    int s = 0;
    for (int i = lo; i < hi; ++i) s += (deg[i] + 4) & ~3;
    sums[t] = s;
    __syncthreads();
    for (int dd = 1; dd < 1024; dd <<= 1) {
        int v = (t >= dd) ? sums[t - dd] : 0;
        __syncthreads();
        sums[t] += v;
        __syncthreads();
    }
    int run = sums[t] - s;  // exclusive prefix
    for (int i = lo; i < hi; ++i) { off[i] = run; cur[i] = run; run += (deg[i] + 4) & ~3; }
    if (t == 1023) off[N] = run;
}
__global__ void k_fill(const int* __restrict__ ei, int E, int N,
                       int* cur, int* __restrict__ csr, int* __restrict__ dstarr) {
    int i = blockIdx.x * blockDim.x + threadIdx.x;
    if (i < E) {
        int s = ei[i], d = ei[E + i];
        int pos = atomicAdd(&cur[d], 1);
        csr[pos] = s;
        dstarr[pos] = d;
    } else if (i < E + N) {
        int nn = i - E;
        int pos = atomicAdd(&cur[nn], 1);
        csr[pos] = nn;
        dstarr[pos] = nn;
    }
}

// ---------------- GEMM: D[M,Nc] = A[M,K] (bf16) @ BT[Nc,K]^T (bf16) ----
template <bool OUTBF>
__global__ __launch_bounds__(256) void k_gemm(
    const unsigned short* __restrict__ A, const unsigned short* __restrict__ BT,
    void* __restrict__ D, int M, int K, int Nc, int tiles_n)
{
    int wid = blockIdx.x * (blockDim.x >> 6) + (threadIdx.x >> 6);
    int tiles_m = (M + 63) >> 6;
    if (wid >= tiles_m * tiles_n) return;
    int lane = threadIdx.x & 63;
    int tm = wid / tiles_n, tn = wid - tm * tiles_n;
    int m0 = tm << 6, n0 = tn << 6;
    int r = lane & 15, q = lane >> 4;

    const unsigned short* Arow[4];
    const unsigned short* Brow[4];
#pragma unroll
    for (int i = 0; i < 4; ++i) {
        int row = m0 + 16 * i + r; row = row < M ? row : M - 1;
        Arow[i] = A + (size_t)row * K + q * 8;
        Brow[i] = BT + (size_t)(n0 + 16 * i + r) * K + q * 8;
    }

    f32x4 acc[4][4] = {};
    bf16x8 a[4], b[4], a2[4], b2[4];
#pragma unroll
    for (int i = 0; i < 4; ++i) {
        a[i] = *(const bf16x8*)(Arow[i]);
        b[i] = *(const bf16x8*)(Brow[i]);
    }
    for (int k0 = 0; k0 < K; k0 += 32) {
        int kn = k0 + 32;
        if (kn < K) {
#pragma unroll
            for (int i = 0; i < 4; ++i) {
                a2[i] = *(const bf16x8*)(Arow[i] + kn);
                b2[i] = *(const bf16x8*)(Brow[i] + kn);
            }
        }
#pragma unroll
        for (int i = 0; i < 4; ++i)
#pragma unroll
            for (int j = 0; j < 4; ++j)
                acc[i][j] = __builtin_amdgcn_mfma_f32_16x16x32_bf16(a[i], b[j], acc[i][j], 0, 0, 0);
        if (kn < K) {
#pragma unroll
            for (int i = 0; i < 4; ++i) { a[i] = a2[i]; b[i] = b2[i]; }
        }
    }
#pragma unroll
    for (int i = 0; i < 4; ++i) {
        int rowb = m0 + 16 * i + q * 4;
#pragma unroll
        for (int rr = 0; rr < 4; ++rr) {
            int row = rowb + rr;
            if (row < M) {
#pragma unroll
                for (int j = 0; j < 4; ++j) {
                    int col = n0 + 16 * j + r;
                    if (OUTBF)
                        ((unsigned short*)D)[(size_t)row * Nc + col] = f2bf(acc[i][j][rr]);
                    else
                        ((float*)D)[(size_t)row * Nc + col] = acc[i][j][rr];
                }
            }
        }
    }
}

// ---------------- attention logits per node: al_s, al_d -------------------
template <int HCt, int Ht, bool INBF>
__global__ __launch_bounds__(256) void k_al(
    const void* __restrict__ h, const float* __restrict__ asrc,
    const float* __restrict__ adst,
    float* __restrict__ als, float* __restrict__ ald, int N)
{
    int wid = blockIdx.x * (blockDim.x >> 6) + (threadIdx.x >> 6);
    if (wid >= N) return;
    int lane = threadIdx.x & 63;
    const int CH = HCt / 64;
    const int Gs = 64 / Ht;  // lanes per head
    float s = 0.f, d = 0.f;
    if constexpr (INBF) {
        const uint4* hr = (const uint4*)((const unsigned short*)h + (size_t)wid * HCt) + lane;
        uint4 hv = *hr;
        unsigned wds[4] = {hv.x, hv.y, hv.z, hv.w};
        const f32x4* as4 = (const f32x4*)(asrc + lane * 8);
        const f32x4* ad4 = (const f32x4*)(adst + lane * 8);
        f32x4 av0 = as4[0], av1 = as4[1], dv0 = ad4[0], dv1 = ad4[1];
        float hf[8];
#pragma unroll
        for (int wv = 0; wv < 4; ++wv) {
            hf[2 * wv]     = __uint_as_float(wds[wv] << 16);
            hf[2 * wv + 1] = __uint_as_float(wds[wv] & 0xffff0000u);
        }
#pragma unroll
        for (int j = 0; j < 4; ++j) {
            s += hf[j] * av0[j] + hf[4 + j] * av1[j];
            d += hf[j] * dv0[j] + hf[4 + j] * dv1[j];
        }
    } else {
        const float* hr = (const float*)h + (size_t)wid * HCt + lane * CH;
#pragma unroll
        for (int j = 0; j < CH; ++j) {
            float hv = hr[j];
            int ch = lane * CH + j;
            s += hv * asrc[ch];
            d += hv * adst[ch];
        }
    }
#pragma unroll
    for (int dd = 1; dd < Gs; dd <<= 1) {
        s += __shfl_xor(s, dd);
        d += __shfl_xor(d, dd);
    }
    if ((lane & (Gs - 1)) == 0) {
        int hh = lane / Gs;
        als[wid * Ht + hh] = s;
        ald[wid * Ht + hh] = d;
    }
}

// ---------------- edge alpha, SoA head planes: alpha[h*Mcap + t] ----------
// pads (csr<0) get alpha=0 so aggr needs no bounds/tail logic
__global__ void k_alpha4(const float* __restrict__ als, const float* __restrict__ ald,
                         const int* __restrict__ csr, const int* __restrict__ dstarr,
                         const int* __restrict__ off, int N,
                         float* __restrict__ alpha, int Mcap)
{
    int t = blockIdx.x * blockDim.x + threadIdx.x;
    if (t >= off[N]) return;
    int s = csr[t];
    if (s < 0) {
#pragma unroll
        for (int h = 0; h < 4; ++h) alpha[(size_t)h * Mcap + t] = 0.f;
        return;
    }
    int d = dstarr[t];
    f32x4 a = *(const f32x4*)(als + (size_t)s * 4);
    f32x4 b = *(const f32x4*)(ald + (size_t)d * 4);
#pragma unroll
    for (int h = 0; h < 4; ++h) {
        float l = a[h] + b[h];
        l = l > 0.f ? l : 0.2f * l;
        alpha[(size_t)h * Mcap + t] = __expf(l);
    }
}

// ---------------- aggr HC=512 H=4, quad-edge inner loop -------------------
// Wave = (node, head); 4 edge-groups x 16 lanes; each group consumes FOUR
// edges/iter: one int4 csr + one f32x4 alpha + 4x uint4 h rows. Segments are
// padded to x4 (alpha=0 on pads) -> no tail logic. Slab-sequential grid
// (head-major) keeps the h gather L2-resident per XCD.
template <bool DOELU>
__global__ __launch_bounds__(256) void k_aggr4b(
    const unsigned short* __restrict__ h, const float* __restrict__ alpha,
    const int* __restrict__ off, const int* __restrict__ csr,
    const float* __restrict__ bias,
    unsigned short* __restrict__ outp, int N, int nodeBlocks, int Mcap)
{
    int head = blockIdx.x / nodeBlocks;
    int nb = blockIdx.x - head * nodeBlocks;
    int n = nb * 4 + (threadIdx.x >> 6);
    if (n >= N) return;
    int lane = threadIdx.x & 63;
    int g = lane >> 4;            // edge group 0..3
    int p = lane & 15;            // channel-lane within group
    int q0 = (off[n] >> 2) + g, q1 = off[n + 1] >> 2;

    float acc[8] = {};
    float den = 0.f;
    const unsigned short* hbase = h + head * 128 + p * 8;
    const int4* csr4 = (const int4*)csr;
    const f32x4* al4 = (const f32x4*)(alpha + (size_t)head * Mcap);

    auto fmaq = [&](float a, const uint4& hq) {
        unsigned wds[4] = {hq.x, hq.y, hq.z, hq.w};
#pragma unroll
        for (int wv = 0; wv < 4; ++wv) {
            acc[2 * wv]     += a * __uint_as_float(wds[wv] << 16);
            acc[2 * wv + 1] += a * __uint_as_float(wds[wv] & 0xffff0000u);
        }
    };

    for (int q = q0; q < q1; q += 4) {
        int4 cs = csr4[q];
        f32x4 av = al4[q];
        int c0 = cs.x < 0 ? 0 : cs.x;   // pads: alpha=0, clamp address
        int c1 = cs.y < 0 ? 0 : cs.y;
        int c2 = cs.z < 0 ? 0 : cs.z;
        int c3 = cs.w < 0 ? 0 : cs.w;
        uint4 h0 = *(const uint4*)(hbase + ((size_t)(unsigned)c0 << 9));
        uint4 h1 = *(const uint4*)(hbase + ((size_t)(unsigned)c1 << 9));
        uint4 h2 = *(const uint4*)(hbase + ((size_t)(unsigned)c2 << 9));
        uint4 h3 = *(const uint4*)(hbase + ((size_t)(unsigned)c3 << 9));
        den += (av[0] + av[1]) + (av[2] + av[3]);
        fmaq(av[0], h0);
        fmaq(av[1], h1);
        fmaq(av[2], h2);
        fmaq(av[3], h3);
    }

    den += __shfl_xor(den, 16);
    den += __shfl_xor(den, 32);
#pragma unroll
    for (int j = 0; j < 8; ++j) {
        acc[j] += __shfl_xor(acc[j], 16);
        acc[j] += __shfl_xor(acc[j], 32);
    }

    if (g == 0) {
        float inv = 1.f / den;
        int cb = head * 128 + p * 8;
        unsigned ww[4];
#pragma unroll
        for (int wv = 0; wv < 4; ++wv) {
            float v0 = acc[2 * wv] * inv + bias[cb + 2 * wv];
            float v1 = acc[2 * wv + 1] * inv + bias[cb + 2 * wv + 1];
            if (DOELU) {
                v0 = v0 > 0.f ? v0 : expm1f(v0);
                v1 = v1 > 0.f ? v1 : expm1f(v1);
            }
            ww[wv] = (unsigned)f2bf(v0) | ((unsigned)f2bf(v1) << 16);
        }
        uint4 o; o.x = ww[0]; o.y = ww[1]; o.z = ww[2]; o.w = ww[3];
        *((uint4*)(outp + (size_t)n * 512 + cb)) = o;
    }
}

// ---------------- layer-3 aggr (HC=64, H=1, f32 h), quad-edge, inline exp -
__global__ __launch_bounds__(256) void k_aggr1b(
    const float* __restrict__ h, const float* __restrict__ als,
    const float* __restrict__ aldv, const int* __restrict__ off,
    const int* __restrict__ csr, const float* __restrict__ bias,
    float* __restrict__ outp, int N)
{
    int n = blockIdx.x * (blockDim.x >> 6) + (threadIdx.x >> 6);
    if (n >= N) return;
    int lane = threadIdx.x & 63;
    int g = lane >> 4;
    int p = lane & 15;
    int q0 = (off[n] >> 2) + g, q1 = off[n + 1] >> 2;
    float aldh = aldv[n];

    float acc[4] = {};
    float den = 0.f;
    const float* hbase = h + p * 4;
    const int4* csr4 = (const int4*)csr;

    auto aof = [&](int ss) -> float {
        int sc = ss < 0 ? 0 : ss;
        float l = als[sc] + aldh;
        l = l > 0.f ? l : 0.2f * l;
        float e = __expf(l);
        return ss < 0 ? 0.f : e;
    };
    auto fmaq = [&](float a, const uint4& hq) {
        den += a;
        acc[0] += a * __uint_as_float(hq.x);
        acc[1] += a * __uint_as_float(hq.y);
        acc[2] += a * __uint_as_float(hq.z);
        acc[3] += a * __uint_as_float(hq.w);
    };

    for (int q = q0; q < q1; q += 4) {
        int4 cs = csr4[q];
        float a0 = aof(cs.x), a1 = aof(cs.y), a2 = aof(cs.z), a3 = aof(cs.w);
        uint4 h0 = *(const uint4*)(hbase + ((size_t)(unsigned)(cs.x < 0 ? 0 : cs.x) << 6));
        uint4 h1 = *(const uint4*)(hbase + ((size_t)(unsigned)(cs.y < 0 ? 0 : cs.y) << 6));
        uint4 h2 = *(const uint4*)(hbase + ((size_t)(unsigned)(cs.z < 0 ? 0 : cs.z) << 6));
        uint4 h3 = *(const uint4*)(hbase + ((size_t)(unsigned)(cs.w < 0 ? 0 : cs.w) << 6));
        fmaq(a0, h0);
        fmaq(a1, h1);
        fmaq(a2, h2);
        fmaq(a3, h3);
    }

    den += __shfl_xor(den, 16);
    den += __shfl_xor(den, 32);
#pragma unroll
    for (int j = 0; j < 4; ++j) {
        acc[j] += __shfl_xor(acc[j], 16);
        acc[j] += __shfl_xor(acc[j], 32);
    }
    if (g == 0) {
        float inv = 1.f / den;
        f32x4 o;
#pragma unroll
        for (int j = 0; j < 4; ++j)
            o[j] = acc[j] * inv + bias[p * 4 + j];
        *((f32x4*)(outp + (size_t)n * 64 + p * 4)) = o;
    }
}

// --------------------------------------------------------------------------
extern "C" void kernel_launch(void* const* d_in, const int* in_sizes, int n_in,
                              void* d_out, int out_size, void* d_ws, size_t ws_size,
                              hipStream_t stream)
{
    const float* x   = (const float*)d_in[0];
    const int*   ei  = (const int*)d_in[1];
    const float* W1  = (const float*)d_in[2];
    const float* as1 = (const float*)d_in[3];
    const float* ad1 = (const float*)d_in[4];
    const float* b1  = (const float*)d_in[5];
    const float* W2  = (const float*)d_in[6];
    const float* as2 = (const float*)d_in[7];
    const float* ad2 = (const float*)d_in[8];
    const float* b2  = (const float*)d_in[9];
    const float* W3  = (const float*)d_in[10];
    const float* as3 = (const float*)d_in[11];
    const float* ad3 = (const float*)d_in[12];
    const float* b3  = (const float*)d_in[13];

    const int DIN = 256, HC = 512, DOUT = 64;
    int N = in_sizes[0] / DIN;
    int E = in_sizes[1] / 2;
    int Mcap = E + 4 * N;  // capacity for 4-padded CSR

    // workspace carve-up
    char* w = (char*)d_ws;
    auto alloc = [&](size_t bytes) -> char* {
        char* p = w;
        w += (bytes + 255) & ~(size_t)255;
        return p;
    };
    int* deg    = (int*)alloc((size_t)N * 4);
    int* cur    = (int*)alloc((size_t)N * 4);
    int* off    = (int*)alloc((size_t)(N + 1) * 4);
    int* csr    = (int*)alloc((size_t)Mcap * 4);
    int* dstarr = (int*)alloc((size_t)Mcap * 4);
    unsigned short* W1T = (unsigned short*)alloc((size_t)HC * DIN * 2);
    unsigned short* W2T = (unsigned short*)alloc((size_t)HC * HC * 2);
    unsigned short* W3T = (unsigned short*)alloc((size_t)DOUT * HC * 2);
    unsigned short* xb  = (unsigned short*)alloc((size_t)N * DIN * 2);
    unsigned short* act = (unsigned short*)alloc((size_t)N * HC * 2);
    unsigned short* hb  = (unsigned short*)alloc((size_t)N * HC * 2);
    float* hbuf  = (float*)alloc((size_t)N * DOUT * 4);
    float* als   = (float*)alloc((size_t)N * 4 * 4);
    float* ald   = (float*)alloc((size_t)N * 4 * 4);
    float* alpha = (float*)alloc((size_t)Mcap * 4 * 4);  // SoA: 4 planes of Mcap

    // ---- build: memset(deg) -> prep(+csr init+hist) -> scan -> fill ----
    hipMemsetAsync(deg, 0, (size_t)N * 4, stream);
    int prep_total = DIN * HC + HC * HC + HC * DOUT + N * DIN + Mcap + E;
    k_prep<<<(prep_total + 255) / 256, 256, 0, stream>>>(
        W1, W1T, W2, W2T, W3, W3T, x, xb, csr, Mcap, ei, E, deg, DIN, HC, DOUT, N);
    k_scan<<<1, 1024, 0, stream>>>(deg, off, cur, N);
    k_fill<<<(E + N + 255) / 256, 256, 0, stream>>>(ei, E, N, cur, csr, dstarr);

    int tiles_m = (N + 63) / 64;
    auto gemm_blocks = [&](int tn) { return (tiles_m * tn + 3) / 4; };
    int nwave_blocks = (N + 3) / 4;
    int nodeBlocks = (N + 3) / 4;
    int alpha_blocks = (Mcap + 255) / 256;

    // ---- layer 1 ----
    k_gemm<true><<<gemm_blocks(HC / 64), 256, 0, stream>>>(xb, W1T, hb, N, DIN, HC, HC / 64);
    k_al<512, 4, true><<<nwave_blocks, 256, 0, stream>>>(hb, as1, ad1, als, ald, N);
    k_alpha4<<<alpha_blocks, 256, 0, stream>>>(als, ald, csr, dstarr, off, N, alpha, Mcap);
    k_aggr4b<true><<<4 * nodeBlocks, 256, 0, stream>>>(hb, alpha, off, csr, b1, act, N, nodeBlocks, Mcap);

    // ---- layer 2 ----
    k_gemm<true><<<gemm_blocks(HC / 64), 256, 0, stream>>>(act, W2T, hb, N, HC, HC, HC / 64);
    k_al<512, 4, true><<<nwave_blocks, 256, 0, stream>>>(hb, as2, ad2, als, ald, N);
    k_alpha4<<<alpha_blocks, 256, 0, stream>>>(als, ald, csr, dstarr, off, N, alpha, Mcap);
    k_aggr4b<true><<<4 * nodeBlocks, 256, 0, stream>>>(hb, alpha, off, csr, b2, act, N, nodeBlocks, Mcap);

    // ---- layer 3 ----
    k_gemm<false><<<gemm_blocks(1), 256, 0, stream>>>(act, W3T, hbuf, N, HC, DOUT, 1);
    k_al<64, 1, false><<<nwave_blocks, 256, 0, stream>>>(hbuf, as3, ad3, als, ald, N);
    k_aggr1b<<<nwave_blocks, 256, 0, stream>>>(hbuf, als, ald, off, csr, b3, (float*)d_out, N);
}